// Round 16
// baseline (166.760 us; speedup 1.0000x reference)
//
#include <hip/hip_runtime.h>
#include <math.h>

#define NUM_TASKS 16
#define B_ROWS    8192

// tile lists: 256-row tiles (L0/L1) and 128-row tiles (L2)
#define NT256 48      // >= sum ceil(rows_t/256)  (3/task worst case)
#define NT128 96      // >= sum ceil(rows_t/128)  (6/task worst case)

typedef __attribute__((ext_vector_type(4))) float f32x4;
typedef __attribute__((ext_vector_type(8))) short bf16x8;
typedef __attribute__((ext_vector_type(4))) short bf16x4;
typedef unsigned short ushort_t;

__device__ __forceinline__ short f2bf(float f) {
    union { float f; unsigned u; } c; c.f = f;
    unsigned u = c.u;
    unsigned r = (u + 0x7FFFu + ((u >> 16) & 1u)) >> 16;
    return (short)r;
}

__device__ __forceinline__ float fast_tanh(float x) {
    float e = __expf(2.0f * x);
    return 1.0f - 2.0f / (e + 1.0f);
}

__device__ __forceinline__ void gld16(const void* g, void* l) {
    __builtin_amdgcn_global_load_lds(
        (const __attribute__((address_space(1))) unsigned int*)g,
        (__attribute__((address_space(3))) unsigned int*)l,
        16, 0, 0);
}

// ---------------------------------------------------------------------------
// Bucket: stable counting sort of rows by task (R3-proven, unpadded offs);
// emits sidx[8192] and two tile lists (256- and 128-row granularity).
// ---------------------------------------------------------------------------
__global__ __launch_bounds__(256) void bucket_kernel(
    const int* __restrict__ task_ids,
    int* __restrict__ sidx,
    int* __restrict__ t256_base, int* __restrict__ t256_task, int* __restrict__ t256_end,
    int* __restrict__ t128_base, int* __restrict__ t128_task, int* __restrict__ t128_end)
{
    __shared__ int cnt[256][NUM_TASKS];
    __shared__ int offs[NUM_TASKS + 1];
    __shared__ int tot[NUM_TASKS];

    const int tid = threadIdx.x;
    #pragma unroll
    for (int t = 0; t < NUM_TASKS; ++t) cnt[tid][t] = 0;
    const int base = tid * (B_ROWS / 256);

    for (int i = 0; i < B_ROWS / 256; ++i) {
        int t = task_ids[base + i];
        cnt[tid][t]++;
    }
    __syncthreads();

    if (tid < NUM_TASKS) {
        int s = 0;
        for (int c = 0; c < 256; ++c) { int v = cnt[c][tid]; cnt[c][tid] = s; s += v; }
        tot[tid] = s;
    }
    __syncthreads();

    if (tid == 0) {
        int s = 0;
        for (int t = 0; t < NUM_TASKS; ++t) { offs[t] = s; s += tot[t]; }
        offs[NUM_TASKS] = s;
        int n2 = 0, n1 = 0;
        for (int t = 0; t < NUM_TASKS; ++t) {
            for (int r = offs[t]; r < offs[t + 1]; r += 256) {
                if (n2 < NT256) {
                    t256_base[n2] = r; t256_task[n2] = t; t256_end[n2] = offs[t + 1];
                    n2++;
                }
            }
            for (int r = offs[t]; r < offs[t + 1]; r += 128) {
                if (n1 < NT128) {
                    t128_base[n1] = r; t128_task[n1] = t; t128_end[n1] = offs[t + 1];
                    n1++;
                }
            }
        }
        for (; n2 < NT256; ++n2) t256_task[n2] = -1;
        for (; n1 < NT128; ++n1) t128_task[n1] = -1;
    }
    __syncthreads();

    for (int i = 0; i < B_ROWS / 256; ++i) {
        int row = base + i;
        int t = task_ids[row];
        int pos = offs[t] + cnt[tid][t];
        cnt[tid][t] = cnt[tid][t] + 1;
        sidx[pos] = row;
    }
}

// ---------------------------------------------------------------------------
// x gather + convert (R2/R3-proven): xs[pos][c] = bf16(x[sidx[pos]][c]).
// ---------------------------------------------------------------------------
__global__ __launch_bounds__(256) void xconv(
    const float* __restrict__ x,
    const int* __restrict__ sidx,
    ushort_t* __restrict__ xs)
{
    const int tid  = threadIdx.x;
    const int pos  = blockIdx.x * 4 + (tid >> 6);
    const int lane = tid & 63;
    const int src  = sidx[pos];
    const float* sp = x + (size_t)src * 512 + lane * 8;
    f32x4 v0 = *(const f32x4*)sp;
    f32x4 v1 = *(const f32x4*)(sp + 4);
    bf16x8 pk;
    pk[0] = f2bf(v0[0]); pk[1] = f2bf(v0[1]);
    pk[2] = f2bf(v0[2]); pk[3] = f2bf(v0[3]);
    pk[4] = f2bf(v1[0]); pk[5] = f2bf(v1[1]);
    pk[6] = f2bf(v1[2]); pk[7] = f2bf(v1[3]);
    *(bf16x8*)(xs + (size_t)pos * 512 + lane * 8) = pk;
}

// ---------------------------------------------------------------------------
// Weight convert + transpose (R2/R3-proven): W[t][k][n] fp32 -> [t][n][k] bf16.
// ---------------------------------------------------------------------------
template<int K, int N>
__global__ __launch_bounds__(256) void wconv(
    const float* __restrict__ W, ushort_t* __restrict__ Wt)
{
    const int t  = blockIdx.z;
    const int kb = blockIdx.y * 64;
    const int nb = blockIdx.x * 64;
    const float* src = W + (size_t)t * K * N;
    ushort_t* dst = Wt + (size_t)t * N * K;

    __shared__ ushort_t tile[64][68];

    const int tid = threadIdx.x;
    {
        int kl  = tid >> 4;
        int nl4 = (tid & 15) * 4;
        #pragma unroll
        for (int r = 0; r < 4; ++r) {
            int k = kl + r * 16;
            f32x4 v = *(const f32x4*)(src + (size_t)(kb + k) * N + nb + nl4);
            tile[nl4 + 0][k] = (ushort_t)f2bf(v[0]);
            tile[nl4 + 1][k] = (ushort_t)f2bf(v[1]);
            tile[nl4 + 2][k] = (ushort_t)f2bf(v[2]);
            tile[nl4 + 3][k] = (ushort_t)f2bf(v[3]);
        }
    }
    __syncthreads();
    {
        int nl = tid >> 2;
        int c  = (tid & 3) * 16;
        bf16x4 v0 = *(const bf16x4*)&tile[nl][c + 0];
        bf16x4 v1 = *(const bf16x4*)&tile[nl][c + 4];
        bf16x4 v2 = *(const bf16x4*)&tile[nl][c + 8];
        bf16x4 v3 = *(const bf16x4*)&tile[nl][c + 12];
        ushort_t* dp = dst + (size_t)(nb + nl) * K + kb + c;
        *(bf16x4*)(dp + 0)  = v0;
        *(bf16x4*)(dp + 4)  = v1;
        *(bf16x4*)(dp + 8)  = v2;
        *(bf16x4*)(dp + 12) = v3;
    }
}

// ---------------------------------------------------------------------------
// Per-task BM-row GEMM, 1 block/CU class. 512 thr = 8 waves (4M x 2N).
// Triple-buffered LDS, depth-2 prefetch, counted vmcnt (R4-proven schedule).
//   A: sorted row-major bf16 [8192][K];  Wt: [T][N][K] bf16.
//   BM=256/BN=128 (L0/L1) or BM=128/BN=64 (L2).
// Staging: pre-swizzled global source (kc0 = spos ^ (srow&7)), linear LDS
// dest via gld16; XOR-swizzled ds reads (R3-proven, 0 bank conflicts).
//   OUT_FINAL=0: bf16 tanh(acc+bias) stored sorted row-major (next layer A).
//   OUT_FINAL=1: fp32 acc+bias scattered via sidx.
// ---------------------------------------------------------------------------
template<int K, int N, int BM, int BN, int OUT_FINAL>
__global__ __launch_bounds__(512, 1) void mlp_gemm(
    const ushort_t* __restrict__ in,
    const ushort_t* __restrict__ wt,
    const float* __restrict__ bias,
    void* __restrict__ out,
    const int* __restrict__ sidx,
    const int* __restrict__ tile_base,
    const int* __restrict__ tile_task,
    const int* __restrict__ tile_end)
{
    constexpr int NSLICE = N / BN;
    constexpr int NTILES = (BM == 256) ? NT256 : NT128;
    constexpr int NB     = NTILES * NSLICE;
    constexpr int NT     = K / 64;               // BK = 64
    constexpr int AR     = BM / 64;              // A stage rounds (4 or 2)
    constexpr int BR     = BN / 64;              // B stage rounds (2 or 1)
    constexpr int BATCH  = AR + BR;              // gld16 per thread per tile
    constexpr int MF     = BM / 4 / 16;          // m-frags per wave (4 or 2)
    constexpr int NF     = BN / 2 / 16;          // n-frags per wave (4 or 2)
    constexpr int LDSE   = (BM + BN) * 64;       // elems per buffer

    // XCD-bijective: NB % 8 == 0; 8 consecutive wgid (one tile's slices)
    // land on one XCD -> A-panel L2-dedup.
    const int orig = blockIdx.x;
    const int wgid = (orig & 7) * (NB / 8) + (orig >> 3);
    const int tile  = wgid / NSLICE;
    const int slice = wgid % NSLICE;

    const int task = tile_task[tile];
    if (task < 0) return;
    const int rowbase = tile_base[tile];
    const int rowend  = tile_end[tile];
    const int n0      = slice * BN;

    __shared__ __align__(16) short LDSb[3][LDSE];

    const int tid  = threadIdx.x;
    const int lane = tid & 63;
    const int wid  = tid >> 6;
    const int wm   = wid >> 1;          // 0..3
    const int wn   = wid & 1;           // 0..1

    f32x4 acc[MF][NF];
    #pragma unroll
    for (int mf = 0; mf < MF; ++mf)
        #pragma unroll
        for (int nf = 0; nf < NF; ++nf)
            acc[mf][nf] = (f32x4){0.f, 0.f, 0.f, 0.f};

    // staging geometry (R5-proven, 512 thr): round = 4096 elems = 64 rows
    const int srow = wid * 8 + (lane >> 3);      // 0..63
    const int spos = lane & 7;
    const int kc0  = spos ^ (srow & 7);

    const ushort_t* Wtt = wt + (size_t)task * N * K;

    const ushort_t* aglob[AR];
    const ushort_t* bglob[BR];
    #pragma unroll
    for (int r = 0; r < AR; ++r) {
        int ga = rowbase + r * 64 + srow;
        if (ga > B_ROWS - 1) ga = B_ROWS - 1;
        aglob[r] = in + (size_t)ga * K + kc0 * 8;
    }
    #pragma unroll
    for (int r = 0; r < BR; ++r)
        bglob[r] = Wtt + (size_t)(n0 + r * 64 + srow) * K + kc0 * 8;

    const int r16 = lane & 15;
    const int khi = lane >> 4;

#define STAGE(BI, TI)                                                         \
    {                                                                         \
        short* Ab_ = &LDSb[(BI)][0] + wid * 512;                              \
        short* Bb_ = &LDSb[(BI)][BM * 64] + wid * 512;                        \
        const size_t ke_ = (size_t)(TI) * 64;                                 \
        _Pragma("unroll")                                                     \
        for (int r_ = 0; r_ < AR; ++r_) gld16(aglob[r_] + ke_, Ab_ + r_ * 4096); \
        _Pragma("unroll")                                                     \
        for (int r_ = 0; r_ < BR; ++r_) gld16(bglob[r_] + ke_, Bb_ + r_ * 4096); \
    }

    STAGE(0, 0)
    STAGE(1, 1)

    #pragma unroll
    for (int t = 0; t < NT; ++t) {
        if (t + 2 < NT) {
            STAGE((t + 2) % 3, t + 2)
            asm volatile("s_waitcnt vmcnt(%0)" :: "n"(2 * BATCH) : "memory");
        } else if (t + 2 == NT) {
            asm volatile("s_waitcnt vmcnt(%0)" :: "n"(BATCH) : "memory");
        } else {
            asm volatile("s_waitcnt vmcnt(0)" ::: "memory");
        }
        asm volatile("s_barrier" ::: "memory");

        const short* Abase = &LDSb[t % 3][0];
        const short* Bbase = &LDSb[t % 3][BM * 64];
        #pragma unroll
        for (int ks = 0; ks < 2; ++ks) {
            bf16x8 a[MF], b[NF];
            const int kc = ks * 4 + khi;
            #pragma unroll
            for (int mf = 0; mf < MF; ++mf) {
                int row = wm * (BM / 4) + mf * 16 + r16;
                a[mf] = *(const bf16x8*)&Abase[row * 64 + (kc ^ (row & 7)) * 8];
            }
            #pragma unroll
            for (int nf = 0; nf < NF; ++nf) {
                int col = wn * (BN / 2) + nf * 16 + r16;
                b[nf] = *(const bf16x8*)&Bbase[col * 64 + (kc ^ (col & 7)) * 8];
            }
            __builtin_amdgcn_s_setprio(1);
            #pragma unroll
            for (int mf = 0; mf < MF; ++mf)
                #pragma unroll
                for (int nf = 0; nf < NF; ++nf)
                    acc[mf][nf] = __builtin_amdgcn_mfma_f32_16x16x32_bf16(
                        a[mf], b[nf], acc[mf][nf], 0, 0, 0);
            __builtin_amdgcn_s_setprio(0);
        }
        asm volatile("s_barrier" ::: "memory");
    }
#undef STAGE

    // ---- epilogue (R3-proven mapping) ----
    {
        const int rg = lane >> 4;
        #pragma unroll
        for (int nf = 0; nf < NF; ++nf) {
            const int col = n0 + wn * (BN / 2) + nf * 16 + r16;
            const float bv = bias[(size_t)task * N + col];
            #pragma unroll
            for (int mf = 0; mf < MF; ++mf) {
                #pragma unroll
                for (int r = 0; r < 4; ++r) {
                    int row_l = wm * (BM / 4) + mf * 16 + rg * 4 + r;
                    int grow = rowbase + row_l;
                    if (grow < rowend) {
                        float v = acc[mf][nf][r] + bv;
                        if (!OUT_FINAL) {
                            v = fast_tanh(v);
                            ((ushort_t*)out)[(size_t)grow * N + col] =
                                (ushort_t)f2bf(v);
                        } else {
                            ((float*)out)[(size_t)sidx[grow] * N + col] = v;
                        }
                    }
                }
            }
        }
    }
}

// ---------------------------------------------------------------------------
extern "C" void kernel_launch(void* const* d_in, const int* in_sizes, int n_in,
                              void* d_out, int out_size, void* d_ws, size_t ws_size,
                              hipStream_t stream)
{
    const float* x        = (const float*)d_in[0];
    const int*   task_ids = (const int*)  d_in[1];
    const float* k0       = (const float*)d_in[2];
    const float* b0       = (const float*)d_in[3];
    const float* k1       = (const float*)d_in[4];
    const float* b1       = (const float*)d_in[5];
    const float* k2       = (const float*)d_in[6];
    const float* b2       = (const float*)d_in[7];
    float* out = (float*)d_out;

    char* ws = (char*)d_ws;
    int* sidx      = (int*)ws;                 // 8192 ints
    int* t256_base = sidx + 8192;
    int* t256_task = t256_base + NT256;
    int* t256_end  = t256_task + NT256;
    int* t128_base = t256_end + NT256;
    int* t128_task = t128_base + NT128;
    int* t128_end  = t128_task + NT128;

    size_t off = 65536;
    ushort_t* xs  = (ushort_t*)(ws + off); off += (size_t)8192 * 512 * 2;
    ushort_t* H0  = (ushort_t*)(ws + off); off += (size_t)8192 * 1024 * 2;
    ushort_t* H1  = (ushort_t*)(ws + off); off += (size_t)8192 * 1024 * 2;
    ushort_t* Wt0 = (ushort_t*)(ws + off); off += (size_t)16 * 512 * 1024 * 2;
    ushort_t* Wt1 = (ushort_t*)(ws + off); off += (size_t)16 * 1024 * 1024 * 2;
    ushort_t* Wt2 = (ushort_t*)(ws + off); off += (size_t)16 * 1024 * 256 * 2;

    bucket_kernel<<<1, 256, 0, stream>>>(task_ids, sidx,
                                         t256_base, t256_task, t256_end,
                                         t128_base, t128_task, t128_end);
    xconv<<<2048, 256, 0, stream>>>(x, sidx, xs);
    wconv< 512, 1024><<<dim3(16,  8, 16), 256, 0, stream>>>(k0, Wt0);
    wconv<1024, 1024><<<dim3(16, 16, 16), 256, 0, stream>>>(k1, Wt1);
    wconv<1024,  256><<<dim3( 4, 16, 16), 256, 0, stream>>>(k2, Wt2);

    // L0: xs[.,512] x W0 -> H0 ; 48 tiles x 8 slices = 384 blocks
    mlp_gemm< 512, 1024, 256, 128, 0><<<NT256 * 8, 512, 0, stream>>>(
        xs, Wt0, b0, H0, sidx, t256_base, t256_task, t256_end);
    // L1: H0 x W1 -> H1 ; 384 blocks
    mlp_gemm<1024, 1024, 256, 128, 0><<<NT256 * 8, 512, 0, stream>>>(
        H0, Wt1, b1, H1, sidx, t256_base, t256_task, t256_end);
    // L2: H1 x W2 -> out ; 96 tiles x 4 slices = 384 blocks
    mlp_gemm<1024,  256, 128,  64, 1><<<NT128 * 4, 512, 0, stream>>>(
        H1, Wt2, b2, out, sidx, t128_base, t128_task, t128_end);
}